// Round 2
// baseline (2660.889 us; speedup 1.0000x reference)
//
#include <hip/hip_runtime.h>
#include <hip/hip_bf16.h>

// ---- problem dims ----
#define BATCH 256
#define TSTEPS 250
#define INDIM 700
#define HID 512
#define BR 4
#define HK 2048          // HID*BR
#define NOUT 20

__device__ __forceinline__ float sigf(float x) { return 1.0f / (1.0f + expf(-x)); }

// ---------------------------------------------------------------------------
// Kernel 1: eff_w = w1 * mask  (2048 x 700)
// ---------------------------------------------------------------------------
__global__ void maskmul(const float* __restrict__ a, const float* __restrict__ m,
                        float* __restrict__ o, int n4) {
    int i = blockIdx.x * blockDim.x + threadIdx.x;
    int stride = gridDim.x * blockDim.x;
    const float4* a4 = (const float4*)a;
    const float4* m4 = (const float4*)m;
    float4* o4 = (float4*)o;
    for (; i < n4; i += stride) {
        float4 av = a4[i], mv = m4[i];
        float4 ov;
        ov.x = av.x * mv.x; ov.y = av.y * mv.y;
        ov.z = av.z * mv.z; ov.w = av.w * mv.w;
        o4[i] = ov;
    }
}

// ---------------------------------------------------------------------------
// Kernel 2: cur(m, n) = sum_k X(m,k) * W(n,k) + b1(n)
//   m = b*tc + tt (chunk-local), X row = b*250 + t0 + tt.
//   Tile 128x128, BK=32, thread tile 8x8, software-pipelined staging.
//   K padded 700 -> 704; last quad (k>=700) zero-filled in LDS (no OOB).
// ---------------------------------------------------------------------------
__device__ __forceinline__ void gemm_fma(float (&acc)[8][8],
                                         const float (*Xs)[132],
                                         const float (*Ws)[132],
                                         int ty, int tx) {
#pragma unroll 8
    for (int kk = 0; kk < 32; ++kk) {
        float4 a0 = *(const float4*)&Xs[kk][ty * 4];
        float4 a1 = *(const float4*)&Xs[kk][64 + ty * 4];
        float4 b0 = *(const float4*)&Ws[kk][tx * 4];
        float4 b1v = *(const float4*)&Ws[kk][64 + tx * 4];
        float ar[8] = {a0.x, a0.y, a0.z, a0.w, a1.x, a1.y, a1.z, a1.w};
        float br[8] = {b0.x, b0.y, b0.z, b0.w, b1v.x, b1v.y, b1v.z, b1v.w};
#pragma unroll
        for (int i = 0; i < 8; ++i)
#pragma unroll
            for (int j = 0; j < 8; ++j)
                acc[i][j] = fmaf(ar[i], br[j], acc[i][j]);
    }
}

__global__ __launch_bounds__(256) void gemm_cur(
    const float* __restrict__ X,   // (256,250,700)
    const float* __restrict__ W,   // eff_w (2048,700)
    const float* __restrict__ b1,  // (2048)
    float* __restrict__ C,         // (256*tc, 2048)
    int tc, int t0) {
    __shared__ float Xs[32][132];
    __shared__ float Ws[32][132];
    const int tid = threadIdx.x;
    const int m0 = blockIdx.y * 128;
    const int n0 = blockIdx.x * 128;

    // staging: thread -> 4 rows (srow + r*32), one k-quad (skq)
    const int srow = tid >> 3;       // 0..31
    const int skq = (tid & 7) * 4;   // 0,4,...,28

    const float* xrows[4];
    const float* wrows[4];
#pragma unroll
    for (int r = 0; r < 4; ++r) {
        int mrow = m0 + srow + r * 32;
        int bb = mrow / tc;
        int tt = mrow - bb * tc;
        xrows[r] = X + (size_t)(bb * TSTEPS + t0 + tt) * INDIM;
        wrows[r] = W + (size_t)(n0 + srow + r * 32) * INDIM;
    }

    const int ty = tid >> 4;  // 0..15 (m)
    const int tx = tid & 15;  // 0..15 (n)

    float acc[8][8];
#pragma unroll
    for (int i = 0; i < 8; ++i)
#pragma unroll
        for (int j = 0; j < 8; ++j) acc[i][j] = 0.0f;

    const float4 z4 = {0.0f, 0.0f, 0.0f, 0.0f};
    float4 xv[4], wv[4];
    // preload tile 0 (skq<700 always at k0=0)
#pragma unroll
    for (int r = 0; r < 4; ++r) {
        xv[r] = *(const float4*)(xrows[r] + skq);
        wv[r] = *(const float4*)(wrows[r] + skq);
    }

    for (int k0 = 0; k0 < 704; k0 += 32) {
        __syncthreads();  // previous compute done reading LDS
#pragma unroll
        for (int r = 0; r < 4; ++r) {
            int row = srow + r * 32;
            Xs[skq + 0][row] = xv[r].x; Xs[skq + 1][row] = xv[r].y;
            Xs[skq + 2][row] = xv[r].z; Xs[skq + 3][row] = xv[r].w;
            Ws[skq + 0][row] = wv[r].x; Ws[skq + 1][row] = wv[r].y;
            Ws[skq + 2][row] = wv[r].z; Ws[skq + 3][row] = wv[r].w;
        }
        __syncthreads();
        // issue next-tile loads before compute (overlap latency)
        int kn = k0 + 32;
        if (kn < 704) {
            bool oob = (kn + skq) >= 700;  // only last tile, skq==28
#pragma unroll
            for (int r = 0; r < 4; ++r) {
                xv[r] = oob ? z4 : *(const float4*)(xrows[r] + kn + skq);
                wv[r] = oob ? z4 : *(const float4*)(wrows[r] + kn + skq);
            }
        }
        gemm_fma(acc, Xs, Ws, ty, tx);
    }

    // epilogue: add bias, store
    float4 bv0 = *(const float4*)(b1 + n0 + tx * 4);
    float4 bv1 = *(const float4*)(b1 + n0 + 64 + tx * 4);
#pragma unroll
    for (int i = 0; i < 8; ++i) {
        int row = m0 + ((i < 4) ? (ty * 4 + i) : (64 + ty * 4 + i - 4));
        float4 o0, o1;
        o0.x = acc[i][0] + bv0.x; o0.y = acc[i][1] + bv0.y;
        o0.z = acc[i][2] + bv0.z; o0.w = acc[i][3] + bv0.w;
        o1.x = acc[i][4] + bv1.x; o1.y = acc[i][5] + bv1.y;
        o1.z = acc[i][6] + bv1.z; o1.w = acc[i][7] + bv1.w;
        *(float4*)(C + (size_t)row * HK + n0 + tx * 4) = o0;
        *(float4*)(C + (size_t)row * HK + n0 + 64 + tx * 4) = o1;
    }
}

// ---------------------------------------------------------------------------
// Kernel 3: sequential SNN scan over the T-chunk. One block per batch,
// thread tid owns neurons h0=tid, h1=tid+256 (4 branches each, registers).
// Emits spike bitmasks (8 x u64 per (b,t)).  No LDS, no barriers.
// ---------------------------------------------------------------------------
__global__ __launch_bounds__(256) void snn_scan(
    const float* __restrict__ Cur,         // (256, tc, 2048)
    const float* __restrict__ tau_m1,      // (512)
    const float* __restrict__ tau_n1,      // (512,4)
    float* __restrict__ st_d,              // (256,2048)
    float* __restrict__ st_m1,             // (256,512)
    unsigned long long* __restrict__ spk,  // (256,250,8)
    int t0, int tc) {
    const int b = blockIdx.x;
    const int tid = threadIdx.x;
    const int h0 = tid, h1 = tid + 256;
    const int wid = tid >> 6, lane = tid & 63;

    const float a0 = sigf(tau_m1[h0]);
    const float a1 = sigf(tau_m1[h1]);
    const float oma0 = 1.0f - a0, oma1 = 1.0f - a1;
    float4 tb0 = *(const float4*)(tau_n1 + h0 * 4);
    float4 tb1 = *(const float4*)(tau_n1 + h1 * 4);
    float be0[4] = {sigf(tb0.x), sigf(tb0.y), sigf(tb0.z), sigf(tb0.w)};
    float be1[4] = {sigf(tb1.x), sigf(tb1.y), sigf(tb1.z), sigf(tb1.w)};
    float ob0[4] = {1.0f - be0[0], 1.0f - be0[1], 1.0f - be0[2], 1.0f - be0[3]};
    float ob1[4] = {1.0f - be1[0], 1.0f - be1[1], 1.0f - be1[2], 1.0f - be1[3]};

    float d0[4], d1[4], m10, m11, s0, s1;
    if (t0 == 0) {
#pragma unroll
        for (int k = 0; k < 4; ++k) { d0[k] = 0.0f; d1[k] = 0.0f; }
        m10 = 0.0f; m11 = 0.0f; s0 = 0.0f; s1 = 0.0f;
    } else {
        float4 dv0 = *(const float4*)(st_d + (size_t)b * HK + tid * 4);
        float4 dv1 = *(const float4*)(st_d + (size_t)b * HK + 1024 + tid * 4);
        d0[0] = dv0.x; d0[1] = dv0.y; d0[2] = dv0.z; d0[3] = dv0.w;
        d1[0] = dv1.x; d1[1] = dv1.y; d1[2] = dv1.z; d1[3] = dv1.w;
        m10 = st_m1[(size_t)b * HID + h0];
        m11 = st_m1[(size_t)b * HID + h1];
        const unsigned long long* sp = spk + ((size_t)b * TSTEPS + (t0 - 1)) * 8;
        s0 = ((sp[wid] >> lane) & 1ull) ? 1.0f : 0.0f;
        s1 = ((sp[4 + wid] >> lane) & 1ull) ? 1.0f : 0.0f;
    }

    const float* cbase = Cur + (size_t)b * tc * HK;
    float4 c0 = *(const float4*)(cbase + tid * 4);
    float4 c1 = *(const float4*)(cbase + 1024 + tid * 4);

    for (int tt = 0; tt < tc; ++tt) {
        float4 n0v, n1v;
        if (tt + 1 < tc) {
            const float* p = cbase + (size_t)(tt + 1) * HK;
            n0v = *(const float4*)(p + tid * 4);
            n1v = *(const float4*)(p + 1024 + tid * 4);
        } else { n0v = c0; n1v = c1; }

        // dendritic membranes: d = beta*d + (1-beta)*c  (match reference form)
        d0[0] = be0[0] * d0[0] + ob0[0] * c0.x;
        d0[1] = be0[1] * d0[1] + ob0[1] * c0.y;
        d0[2] = be0[2] * d0[2] + ob0[2] * c0.z;
        d0[3] = be0[3] * d0[3] + ob0[3] * c0.w;
        d1[0] = be1[0] * d1[0] + ob1[0] * c1.x;
        d1[1] = be1[1] * d1[1] + ob1[1] * c1.y;
        d1[2] = be1[2] * d1[2] + ob1[2] * c1.z;
        d1[3] = be1[3] * d1[3] + ob1[3] * c1.w;
        float l0 = (d0[0] + d0[1]) + (d0[2] + d0[3]);
        float l1 = (d1[0] + d1[1]) + (d1[2] + d1[3]);

        // soma: soft reset with previous spike (VTH = 1)
        m10 = a0 * m10 + oma0 * l0 - s0;
        m11 = a1 * m11 + oma1 * l1 - s1;
        bool sp0 = m10 > 1.0f;
        bool sp1 = m11 > 1.0f;
        s0 = sp0 ? 1.0f : 0.0f;
        s1 = sp1 ? 1.0f : 0.0f;

        unsigned long long mk0 = __ballot(sp0);
        unsigned long long mk1 = __ballot(sp1);
        if (lane == 0) {
            unsigned long long* o = spk + ((size_t)b * TSTEPS + (t0 + tt)) * 8;
            o[wid] = mk0;
            o[4 + wid] = mk1;
        }
        c0 = n0v; c1 = n1v;
    }

    float4 dv0 = {d0[0], d0[1], d0[2], d0[3]};
    float4 dv1 = {d1[0], d1[1], d1[2], d1[3]};
    *(float4*)(st_d + (size_t)b * HK + tid * 4) = dv0;
    *(float4*)(st_d + (size_t)b * HK + 1024 + tid * 4) = dv1;
    st_m1[(size_t)b * HID + h0] = m10;
    st_m1[(size_t)b * HID + h1] = m11;
}

// ---------------------------------------------------------------------------
// Kernel 4: out(b,t,o) = b2(o) + sum_h spk(b,t,h) * w2(o,h)  — bit-sparse.
// Writes directly into d_out in (B,T,O) layout (pre-filter values).
// ---------------------------------------------------------------------------
__global__ __launch_bounds__(256) void spk_gemm(
    const unsigned long long* __restrict__ spk,  // (256,250,8)
    const float* __restrict__ w2,                // (20,512)
    const float* __restrict__ b2,                // (20)
    float* __restrict__ Y) {                     // (256,250,20)
    __shared__ float w2t[512][21];
    const int t = blockIdx.x;
    const int b = threadIdx.x;
    for (int i = threadIdx.x; i < HID * NOUT; i += 256) {
        int o = i / HID;
        int h = i - o * HID;
        w2t[h][o] = w2[i];
    }
    __syncthreads();
    float acc[NOUT];
#pragma unroll
    for (int o = 0; o < NOUT; ++o) acc[o] = b2[o];
    const unsigned long long* sp = spk + ((size_t)b * TSTEPS + t) * 8;
#pragma unroll
    for (int w = 0; w < 8; ++w) {
        unsigned long long m = sp[w];
        while (m) {
            int i = __ffsll((long long)m) - 1;
            m &= m - 1;
            const float* col = &w2t[w * 64 + i][0];
#pragma unroll
            for (int o = 0; o < NOUT; ++o) acc[o] += col[o];
        }
    }
    float* outp = Y + ((size_t)b * TSTEPS + t) * NOUT;
#pragma unroll
    for (int o = 0; o < NOUT; ++o) outp[o] = acc[o];
}

// ---------------------------------------------------------------------------
// Kernel 5: in-place leaky readout filter per (b,o) over t.
// ---------------------------------------------------------------------------
__global__ __launch_bounds__(256) void filter_out(
    float* __restrict__ Y, const float* __restrict__ tau_m2) {
    int gid = blockIdx.x * 256 + threadIdx.x;
    if (gid >= BATCH * NOUT) return;
    int b = gid / NOUT;
    int o = gid - b * NOUT;
    float a2 = sigf(tau_m2[o]);
    float oma = 1.0f - a2;
    float m2 = 0.0f;
    float* p = Y + (size_t)b * TSTEPS * NOUT + o;
    for (int t = 0; t < TSTEPS; ++t) {
        m2 = a2 * m2 + oma * p[(size_t)t * NOUT];
        p[(size_t)t * NOUT] = m2;
    }
}

// ---------------------------------------------------------------------------
extern "C" void kernel_launch(void* const* d_in, const int* in_sizes, int n_in,
                              void* d_out, int out_size, void* d_ws, size_t ws_size,
                              hipStream_t stream) {
    const float* x      = (const float*)d_in[0];
    const float* w1     = (const float*)d_in[1];
    const float* b1     = (const float*)d_in[2];
    const float* tau_m1 = (const float*)d_in[3];
    const float* tau_n1 = (const float*)d_in[4];
    const float* mask   = (const float*)d_in[5];
    const float* w2     = (const float*)d_in[6];
    const float* b2     = (const float*)d_in[7];
    const float* tau_m2 = (const float*)d_in[8];
    float* out = (float*)d_out;

    char* ws = (char*)d_ws;
    size_t off = 0;
    auto walloc = [&](size_t bytes) -> void* {
        void* p = ws + off;
        off += (bytes + 255) & ~(size_t)255;
        return p;
    };
    float* effw = (float*)walloc((size_t)HK * INDIM * 4);             // 5.73 MB
    unsigned long long* spk =
        (unsigned long long*)walloc((size_t)BATCH * TSTEPS * 8 * 8);  // 4.10 MB
    float* st_d = (float*)walloc((size_t)BATCH * HK * 4);             // 2.10 MB
    float* st_m1= (float*)walloc((size_t)BATCH * HID * 4);            // 0.52 MB

    size_t avail = (ws_size > off) ? ws_size - off : 0;
    size_t perT = (size_t)BATCH * HK * 4;  // 2 MB per timestep
    int Tc = (int)(avail / perT);
    if (Tc > TSTEPS) Tc = TSTEPS;
    if (Tc < 1) Tc = 1;
    float* cur = (float*)(ws + off);

    maskmul<<<256, 256, 0, stream>>>(w1, mask, effw, HK * INDIM / 4);

    for (int t0 = 0; t0 < TSTEPS; t0 += Tc) {
        int tc = (TSTEPS - t0 < Tc) ? (TSTEPS - t0) : Tc;
        dim3 grid(HK / 128, 2 * tc);
        gemm_cur<<<grid, 256, 0, stream>>>(x, effw, b1, cur, tc, t0);
        snn_scan<<<BATCH, 256, 0, stream>>>(cur, tau_m1, tau_n1, st_d, st_m1,
                                            spk, t0, tc);
    }
    spk_gemm<<<TSTEPS, 256, 0, stream>>>(spk, w2, b2, out);
    filter_out<<<(BATCH * NOUT + 255) / 256, 256, 0, stream>>>(out, tau_m2);
}

// Round 4
// 1429.487 us; speedup vs baseline: 1.8614x; 1.8614x over previous
//
#include <hip/hip_runtime.h>
#include <hip/hip_bf16.h>
#include <hip/hip_fp16.h>

// ---- problem dims ----
#define BATCH 256
#define TSTEPS 250
#define INDIM 700
#define KPAD 704         // 700 padded to 11*64
#define HID 512
#define HK 2048          // HID*BR
#define NOUT 20
#define KSEG 11          // K-tiles of 64 per 704-segment
#define KTILES 33        // 3 products * 11

typedef __attribute__((ext_vector_type(8))) _Float16 f16x8;
typedef __attribute__((ext_vector_type(4))) _Float16 f16x4;
typedef __attribute__((ext_vector_type(4))) float f32x4;

__device__ __forceinline__ float sigf(float x) { return 1.0f / (1.0f + expf(-x)); }

__device__ __forceinline__ void gload_lds16(const void* g, void* l) {
    __builtin_amdgcn_global_load_lds(
        (const __attribute__((address_space(1))) void*)g,
        (__attribute__((address_space(3))) void*)l, 16, 0, 0);
}

// ---------------------------------------------------------------------------
// Kernel 1a: split x chunk into fp16 hi/lo, chunk-local rows (b*tc+tt).
// ---------------------------------------------------------------------------
__global__ __launch_bounds__(192) void split_x(
    const float* __restrict__ x, _Float16* __restrict__ X0,
    _Float16* __restrict__ X1, int t0, int tc) {
    const int row = blockIdx.x;                 // 0 .. 256*tc-1
    const int b = row / tc, tt = row - b * tc;
    const float* xr = x + (size_t)(b * TSTEPS + t0 + tt) * INDIM;
    const int k = threadIdx.x * 4;
    if (k >= KPAD) return;
    float4 v = {0.f, 0.f, 0.f, 0.f};
    if (k < INDIM) v = *(const float4*)(xr + k);   // 700 % 4 == 0: full quads
    f16x4 h, l;
    h[0] = (_Float16)v.x; l[0] = (_Float16)(v.x - (float)h[0]);
    h[1] = (_Float16)v.y; l[1] = (_Float16)(v.y - (float)h[1]);
    h[2] = (_Float16)v.z; l[2] = (_Float16)(v.z - (float)h[2]);
    h[3] = (_Float16)v.w; l[3] = (_Float16)(v.w - (float)h[3]);
    *(f16x4*)(X0 + (size_t)row * KPAD + k) = h;
    *(f16x4*)(X1 + (size_t)row * KPAD + k) = l;
}

// ---------------------------------------------------------------------------
// Kernel 1b: W = w1*mask split into fp16 hi/lo (2048 x 704, zero-padded).
// ---------------------------------------------------------------------------
__global__ __launch_bounds__(192) void split_w(
    const float* __restrict__ w1, const float* __restrict__ mask,
    _Float16* __restrict__ W0, _Float16* __restrict__ W1) {
    const int n = blockIdx.x;
    const int k = threadIdx.x * 4;
    if (k >= KPAD) return;
    float4 e = {0.f, 0.f, 0.f, 0.f};
    if (k < INDIM) {
        float4 wv = *(const float4*)(w1 + (size_t)n * INDIM + k);
        float4 mv = *(const float4*)(mask + (size_t)n * INDIM + k);
        e.x = wv.x * mv.x; e.y = wv.y * mv.y;
        e.z = wv.z * mv.z; e.w = wv.w * mv.w;
    }
    f16x4 h, l;
    h[0] = (_Float16)e.x; l[0] = (_Float16)(e.x - (float)h[0]);
    h[1] = (_Float16)e.y; l[1] = (_Float16)(e.y - (float)h[1]);
    h[2] = (_Float16)e.z; l[2] = (_Float16)(e.z - (float)h[2]);
    h[3] = (_Float16)e.w; l[3] = (_Float16)(e.w - (float)h[3]);
    *(f16x4*)(W0 + (size_t)n * KPAD + k) = h;
    *(f16x4*)(W1 + (size_t)n * KPAD + k) = l;
}

// ---------------------------------------------------------------------------
// Kernel 2: MFMA GEMM.  cur[m][n] = sum_k X[m][k]*W[n][k] + b1[n], fp32 out.
// K' = 2112 = 3 segments of 704: X0*W0 + X0*W1 + X1*W0 (split-fp16 = fp32-
// quality).  128x128 tile, BK=64, 4 waves (2x2 of 64x64), 16x16x32 f16 MFMA,
// global_load_lds width-16 staging, 2-barrier loop (m97 structure).
// ---------------------------------------------------------------------------
__global__ __launch_bounds__(256) void gemm_f16(
    const _Float16* __restrict__ X0, const _Float16* __restrict__ X1,
    const _Float16* __restrict__ W0, const _Float16* __restrict__ W1,
    const float* __restrict__ b1, float* __restrict__ C) {
    __shared__ __align__(16) _Float16 As[128 * 64];
    __shared__ __align__(16) _Float16 Bs[128 * 64];
    const int tid = threadIdx.x;
    const int w = tid >> 6, lane = tid & 63;
    const int m0 = blockIdx.y * 128, n0 = blockIdx.x * 128;

    // staging: wave w stages rows [w*32, w*32+32) of both tiles.
    // instr i: 8 rows; lane -> row + (lane>>3), halfword col (lane&7)*8
    const int srOff = w * 32 + (lane >> 3);
    const int scol = (lane & 7) * 8;

    // compute: wave (wr,wc) owns 64x64 at (wr*64, wc*64)
    const int ar = (w >> 1) * 64, bc = (w & 1) * 64;
    const int lm = lane & 15, lk = (lane >> 4) * 8;

    f32x4 acc[4][4];
#pragma unroll
    for (int m = 0; m < 4; ++m)
#pragma unroll
        for (int n = 0; n < 4; ++n) acc[m][n] = (f32x4){0.f, 0.f, 0.f, 0.f};

    int kk = 0, seg = 0;
    for (int kt = 0; kt < KTILES; ++kt) {
        const _Float16* Xp = (seg < 2) ? X0 : X1;
        const _Float16* Wp = (seg == 1) ? W1 : W0;
        const int k0 = kk * 64;
        // stage A and B tiles (4 + 4 global_load_lds per wave)
#pragma unroll
        for (int i = 0; i < 4; ++i) {
            const _Float16* g =
                Xp + (size_t)(m0 + srOff + i * 8) * KPAD + k0 + scol;
            gload_lds16(g, (void*)&As[(w * 32 + i * 8) * 64]);
        }
#pragma unroll
        for (int i = 0; i < 4; ++i) {
            const _Float16* g =
                Wp + (size_t)(n0 + srOff + i * 8) * KPAD + k0 + scol;
            gload_lds16(g, (void*)&Bs[(w * 32 + i * 8) * 64]);
        }
        __syncthreads();
#pragma unroll
        for (int ks = 0; ks < 2; ++ks) {
            f16x8 af[4], bf[4];
#pragma unroll
            for (int m = 0; m < 4; ++m)
                af[m] = *(const f16x8*)&As[(ar + m * 16 + lm) * 64 + ks * 32 + lk];
#pragma unroll
            for (int n = 0; n < 4; ++n)
                bf[n] = *(const f16x8*)&Bs[(bc + n * 16 + lm) * 64 + ks * 32 + lk];
#pragma unroll
            for (int m = 0; m < 4; ++m)
#pragma unroll
                for (int n = 0; n < 4; ++n)
                    acc[m][n] = __builtin_amdgcn_mfma_f32_16x16x32_f16(
                        af[m], bf[n], acc[m][n], 0, 0, 0);
        }
        __syncthreads();
        if (++kk == KSEG) { kk = 0; ++seg; }
    }

    // epilogue: C/D layout col=lane&15, row=(lane>>4)*4+reg
    const int crow0 = m0 + ar + (lane >> 4) * 4;
    const int ccol0 = n0 + bc + lm;
#pragma unroll
    for (int n = 0; n < 4; ++n) {
        const float bias = b1[ccol0 + n * 16];
#pragma unroll
        for (int m = 0; m < 4; ++m) {
            f32x4 v = acc[m][n];
            const int r0 = crow0 + m * 16;
#pragma unroll
            for (int r = 0; r < 4; ++r)
                C[(size_t)(r0 + r) * HK + ccol0 + n * 16] = v[r] + bias;
        }
    }
}

// ---------------------------------------------------------------------------
// Kernel 3: sequential SNN scan over the T-chunk (unchanged, verified).
// ---------------------------------------------------------------------------
__global__ __launch_bounds__(256) void snn_scan(
    const float* __restrict__ Cur,         // (256, tc, 2048)
    const float* __restrict__ tau_m1,      // (512)
    const float* __restrict__ tau_n1,      // (512,4)
    float* __restrict__ st_d,              // (256,2048)
    float* __restrict__ st_m1,             // (256,512)
    unsigned long long* __restrict__ spk,  // (256,250,8)
    int t0, int tc) {
    const int b = blockIdx.x;
    const int tid = threadIdx.x;
    const int h0 = tid, h1 = tid + 256;
    const int wid = tid >> 6, lane = tid & 63;

    const float a0 = sigf(tau_m1[h0]);
    const float a1 = sigf(tau_m1[h1]);
    const float oma0 = 1.0f - a0, oma1 = 1.0f - a1;
    float4 tb0 = *(const float4*)(tau_n1 + h0 * 4);
    float4 tb1 = *(const float4*)(tau_n1 + h1 * 4);
    float be0[4] = {sigf(tb0.x), sigf(tb0.y), sigf(tb0.z), sigf(tb0.w)};
    float be1[4] = {sigf(tb1.x), sigf(tb1.y), sigf(tb1.z), sigf(tb1.w)};
    float ob0[4] = {1.0f - be0[0], 1.0f - be0[1], 1.0f - be0[2], 1.0f - be0[3]};
    float ob1[4] = {1.0f - be1[0], 1.0f - be1[1], 1.0f - be1[2], 1.0f - be1[3]};

    float d0[4], d1[4], m10, m11, s0, s1;
    if (t0 == 0) {
#pragma unroll
        for (int k = 0; k < 4; ++k) { d0[k] = 0.0f; d1[k] = 0.0f; }
        m10 = 0.0f; m11 = 0.0f; s0 = 0.0f; s1 = 0.0f;
    } else {
        float4 dv0 = *(const float4*)(st_d + (size_t)b * HK + tid * 4);
        float4 dv1 = *(const float4*)(st_d + (size_t)b * HK + 1024 + tid * 4);
        d0[0] = dv0.x; d0[1] = dv0.y; d0[2] = dv0.z; d0[3] = dv0.w;
        d1[0] = dv1.x; d1[1] = dv1.y; d1[2] = dv1.z; d1[3] = dv1.w;
        m10 = st_m1[(size_t)b * HID + h0];
        m11 = st_m1[(size_t)b * HID + h1];
        const unsigned long long* sp = spk + ((size_t)b * TSTEPS + (t0 - 1)) * 8;
        s0 = ((sp[wid] >> lane) & 1ull) ? 1.0f : 0.0f;
        s1 = ((sp[4 + wid] >> lane) & 1ull) ? 1.0f : 0.0f;
    }

    const float* cbase = Cur + (size_t)b * tc * HK;
    float4 c0 = *(const float4*)(cbase + tid * 4);
    float4 c1 = *(const float4*)(cbase + 1024 + tid * 4);

    for (int tt = 0; tt < tc; ++tt) {
        float4 n0v, n1v;
        if (tt + 1 < tc) {
            const float* p = cbase + (size_t)(tt + 1) * HK;
            n0v = *(const float4*)(p + tid * 4);
            n1v = *(const float4*)(p + 1024 + tid * 4);
        } else { n0v = c0; n1v = c1; }

        d0[0] = be0[0] * d0[0] + ob0[0] * c0.x;
        d0[1] = be0[1] * d0[1] + ob0[1] * c0.y;
        d0[2] = be0[2] * d0[2] + ob0[2] * c0.z;
        d0[3] = be0[3] * d0[3] + ob0[3] * c0.w;
        d1[0] = be1[0] * d1[0] + ob1[0] * c1.x;
        d1[1] = be1[1] * d1[1] + ob1[1] * c1.y;
        d1[2] = be1[2] * d1[2] + ob1[2] * c1.z;
        d1[3] = be1[3] * d1[3] + ob1[3] * c1.w;
        float l0 = (d0[0] + d0[1]) + (d0[2] + d0[3]);
        float l1 = (d1[0] + d1[1]) + (d1[2] + d1[3]);

        m10 = a0 * m10 + oma0 * l0 - s0;
        m11 = a1 * m11 + oma1 * l1 - s1;
        bool sp0 = m10 > 1.0f;
        bool sp1 = m11 > 1.0f;
        s0 = sp0 ? 1.0f : 0.0f;
        s1 = sp1 ? 1.0f : 0.0f;

        unsigned long long mk0 = __ballot(sp0);
        unsigned long long mk1 = __ballot(sp1);
        if (lane == 0) {
            unsigned long long* o = spk + ((size_t)b * TSTEPS + (t0 + tt)) * 8;
            o[wid] = mk0;
            o[4 + wid] = mk1;
        }
        c0 = n0v; c1 = n1v;
    }

    float4 dv0 = {d0[0], d0[1], d0[2], d0[3]};
    float4 dv1 = {d1[0], d1[1], d1[2], d1[3]};
    *(float4*)(st_d + (size_t)b * HK + tid * 4) = dv0;
    *(float4*)(st_d + (size_t)b * HK + 1024 + tid * 4) = dv1;
    st_m1[(size_t)b * HID + h0] = m10;
    st_m1[(size_t)b * HID + h1] = m11;
}

// ---------------------------------------------------------------------------
// Kernel 4: out(b,t,o) = b2(o) + sum_h spk(b,t,h)*w2(o,h), bit-sparse.
// ---------------------------------------------------------------------------
__global__ __launch_bounds__(256) void spk_gemm(
    const unsigned long long* __restrict__ spk,  // (256,250,8)
    const float* __restrict__ w2,                // (20,512)
    const float* __restrict__ b2,                // (20)
    float* __restrict__ Y) {                     // (256,250,20)
    __shared__ float w2t[512][21];
    const int t = blockIdx.x;
    const int b = threadIdx.x;
    for (int i = threadIdx.x; i < HID * NOUT; i += 256) {
        int o = i / HID;
        int h = i - o * HID;
        w2t[h][o] = w2[i];
    }
    __syncthreads();
    float acc[NOUT];
#pragma unroll
    for (int o = 0; o < NOUT; ++o) acc[o] = b2[o];
    const unsigned long long* sp = spk + ((size_t)b * TSTEPS + t) * 8;
#pragma unroll
    for (int w = 0; w < 8; ++w) {
        unsigned long long m = sp[w];
        while (m) {
            int i = __ffsll((long long)m) - 1;
            m &= m - 1;
            const float* col = &w2t[w * 64 + i][0];
#pragma unroll
            for (int o = 0; o < NOUT; ++o) acc[o] += col[o];
        }
    }
    float* outp = Y + ((size_t)b * TSTEPS + t) * NOUT;
#pragma unroll
    for (int o = 0; o < NOUT; ++o) outp[o] = acc[o];
}

// ---------------------------------------------------------------------------
// Kernel 5: in-place leaky readout filter per (b,o) over t.
// ---------------------------------------------------------------------------
__global__ __launch_bounds__(256) void filter_out(
    float* __restrict__ Y, const float* __restrict__ tau_m2) {
    int gid = blockIdx.x * 256 + threadIdx.x;
    if (gid >= BATCH * NOUT) return;
    int b = gid / NOUT;
    int o = gid - b * NOUT;
    float a2 = sigf(tau_m2[o]);
    float oma = 1.0f - a2;
    float m2 = 0.0f;
    float* p = Y + (size_t)b * TSTEPS * NOUT + o;
    for (int t = 0; t < TSTEPS; ++t) {
        m2 = a2 * m2 + oma * p[(size_t)t * NOUT];
        p[(size_t)t * NOUT] = m2;
    }
}

// ---------------------------------------------------------------------------
extern "C" void kernel_launch(void* const* d_in, const int* in_sizes, int n_in,
                              void* d_out, int out_size, void* d_ws, size_t ws_size,
                              hipStream_t stream) {
    const float* x      = (const float*)d_in[0];
    const float* w1     = (const float*)d_in[1];
    const float* b1     = (const float*)d_in[2];
    const float* tau_m1 = (const float*)d_in[3];
    const float* tau_n1 = (const float*)d_in[4];
    const float* mask   = (const float*)d_in[5];
    const float* w2     = (const float*)d_in[6];
    const float* b2     = (const float*)d_in[7];
    const float* tau_m2 = (const float*)d_in[8];
    float* out = (float*)d_out;

    char* ws = (char*)d_ws;
    size_t off = 0;
    auto walloc = [&](size_t bytes) -> void* {
        void* p = ws + off;
        off += (bytes + 255) & ~(size_t)255;
        return p;
    };
    _Float16* W0 = (_Float16*)walloc((size_t)HK * KPAD * 2);          // 2.88 MB
    _Float16* W1 = (_Float16*)walloc((size_t)HK * KPAD * 2);          // 2.88 MB
    unsigned long long* spk =
        (unsigned long long*)walloc((size_t)BATCH * TSTEPS * 8 * 8);  // 4.10 MB
    float* st_d  = (float*)walloc((size_t)BATCH * HK * 4);            // 2.10 MB
    float* st_m1 = (float*)walloc((size_t)BATCH * HID * 4);           // 0.52 MB

    // per-timestep: cur (fp32) + X0 + X1 (fp16)
    const size_t perT = (size_t)BATCH * HK * 4 + 2 * (size_t)BATCH * KPAD * 2;
    size_t avail = (ws_size > off + 4096) ? ws_size - off - 4096 : 0;
    int Tc = (int)(avail / perT);
    if (Tc > TSTEPS) Tc = TSTEPS;
    if (Tc < 1) Tc = 1;
    _Float16* X0 = (_Float16*)walloc((size_t)BATCH * Tc * KPAD * 2);
    _Float16* X1 = (_Float16*)walloc((size_t)BATCH * Tc * KPAD * 2);
    float* cur   = (float*)walloc((size_t)BATCH * Tc * HK * 4);

    split_w<<<HK, 192, 0, stream>>>(w1, mask, W0, W1);

    for (int t0 = 0; t0 < TSTEPS; t0 += Tc) {
        int tc = (TSTEPS - t0 < Tc) ? (TSTEPS - t0) : Tc;
        split_x<<<BATCH * tc, 192, 0, stream>>>(x, X0, X1, t0, tc);
        dim3 grid(HK / 128, (BATCH * tc) / 128);
        gemm_f16<<<grid, 256, 0, stream>>>(X0, X1, W0, W1, b1, cur);
        snn_scan<<<BATCH, 256, 0, stream>>>(cur, tau_m1, tau_n1, st_d, st_m1,
                                            spk, t0, tc);
    }
    spk_gemm<<<TSTEPS, 256, 0, stream>>>(spk, w2, b2, out);
    filter_out<<<(BATCH * NOUT + 255) / 256, 256, 0, stream>>>(out, tau_m2);
}

// Round 5
// 1132.910 us; speedup vs baseline: 2.3487x; 1.2618x over previous
//
#include <hip/hip_runtime.h>
#include <hip/hip_bf16.h>
#include <hip/hip_fp16.h>

// ---- problem dims ----
#define BATCH 256
#define TSTEPS 250
#define INDIM 700
#define KPAD 704         // 700 padded to 704 (22 chunks of 32)
#define HID 512
#define HK 2048          // HID*BR
#define NOUT 20
#define NCHUNK 66        // 3 segments * 22 k-chunks of 32

typedef __attribute__((ext_vector_type(8))) _Float16 f16x8;
typedef __attribute__((ext_vector_type(4))) _Float16 f16x4;
typedef __attribute__((ext_vector_type(4))) float f32x4;

__device__ __forceinline__ float sigf(float x) { return 1.0f / (1.0f + expf(-x)); }

__device__ __forceinline__ void gload_lds16(const void* g, void* l) {
    __builtin_amdgcn_global_load_lds(
        (const __attribute__((address_space(1))) void*)g,
        (__attribute__((address_space(3))) void*)l, 16, 0, 0);
}

// ---------------------------------------------------------------------------
// Kernel 1a: split x chunk into fp16 hi/lo, chunk-local rows (b*tc+tt).
// ---------------------------------------------------------------------------
__global__ __launch_bounds__(192) void split_x(
    const float* __restrict__ x, _Float16* __restrict__ X0,
    _Float16* __restrict__ X1, int t0, int tc) {
    const int row = blockIdx.x;                 // 0 .. 256*tc-1
    const int b = row / tc, tt = row - b * tc;
    const float* xr = x + (size_t)(b * TSTEPS + t0 + tt) * INDIM;
    const int k = threadIdx.x * 4;
    if (k >= KPAD) return;
    float4 v = {0.f, 0.f, 0.f, 0.f};
    if (k < INDIM) v = *(const float4*)(xr + k);   // 700 % 4 == 0: full quads
    f16x4 h, l;
    h[0] = (_Float16)v.x; l[0] = (_Float16)(v.x - (float)h[0]);
    h[1] = (_Float16)v.y; l[1] = (_Float16)(v.y - (float)h[1]);
    h[2] = (_Float16)v.z; l[2] = (_Float16)(v.z - (float)h[2]);
    h[3] = (_Float16)v.w; l[3] = (_Float16)(v.w - (float)h[3]);
    *(f16x4*)(X0 + (size_t)row * KPAD + k) = h;
    *(f16x4*)(X1 + (size_t)row * KPAD + k) = l;
}

// ---------------------------------------------------------------------------
// Kernel 1b: W = w1*mask split into fp16 hi/lo (2048 x 704, zero-padded).
// ---------------------------------------------------------------------------
__global__ __launch_bounds__(192) void split_w(
    const float* __restrict__ w1, const float* __restrict__ mask,
    _Float16* __restrict__ W0, _Float16* __restrict__ W1) {
    const int n = blockIdx.x;
    const int k = threadIdx.x * 4;
    if (k >= KPAD) return;
    float4 e = {0.f, 0.f, 0.f, 0.f};
    if (k < INDIM) {
        float4 wv = *(const float4*)(w1 + (size_t)n * INDIM + k);
        float4 mv = *(const float4*)(mask + (size_t)n * INDIM + k);
        e.x = wv.x * mv.x; e.y = wv.y * mv.y;
        e.z = wv.z * mv.z; e.w = wv.w * mv.w;
    }
    f16x4 h, l;
    h[0] = (_Float16)e.x; l[0] = (_Float16)(e.x - (float)h[0]);
    h[1] = (_Float16)e.y; l[1] = (_Float16)(e.y - (float)h[1]);
    h[2] = (_Float16)e.z; l[2] = (_Float16)(e.z - (float)h[2]);
    h[3] = (_Float16)e.w; l[3] = (_Float16)(e.w - (float)h[3]);
    *(f16x4*)(W0 + (size_t)n * KPAD + k) = h;
    *(f16x4*)(W1 + (size_t)n * KPAD + k) = l;
}

// ---------------------------------------------------------------------------
// Kernel 2: 8-phase-style MFMA GEMM (T2+T3+T4+T5).
// C tile 256x256, 512 thr = 8 waves (2M x 4N), per-wave 128x64 output.
// K' = 2112 = 66 chunks of 32 (3 segments x 22): X0*W0 + X0*W1 + X1*W0.
// LDS ring of 4 chunk-buffers (A 16KB + B 16KB each) = 128 KB dynamic.
// Per chunk, 2 phases: {ds_read subtile; stage future slot (2 gload_lds);
// barrier; setprio(1); 16 MFMA; setprio(0); [vmcnt(4) odd]; barrier}.
// XOR swizzle both-sides: physical [128 prow][8 x 16B], chunk
// p = ((r&1)*4+c) ^ (pr&7); staged via pre-swizzled GLOBAL source (rule #21).
// ---------------------------------------------------------------------------
__global__ __launch_bounds__(512, 1) void gemm_f16(
    const _Float16* __restrict__ X0, const _Float16* __restrict__ X1,
    const _Float16* __restrict__ W0, const _Float16* __restrict__ W1,
    const float* __restrict__ b1, float* __restrict__ C) {
    extern __shared__ char smem[];   // 131072 bytes: 4 slots x (16KB A + 16KB B)
    const int tid = threadIdx.x;
    const int w = tid >> 6, lane = tid & 63;
    const int wm = w >> 2, wn = w & 3;           // wave: 2M x 4N
    const int lm = lane & 15, cfr = lane >> 4;   // frag row / 16B-chunk

    // XCD-aware swizzle (bijective: nwg = 8*tc, nwg%8==0)
    const int nwg = gridDim.x;
    const int cpx = nwg >> 3;
    const int o = blockIdx.x;
    const int wg = (o & 7) * cpx + (o >> 3);
    const int n0 = (wg & 7) * 256;
    const int m0 = (wg >> 3) * 256;

    // ---- staging precompute: physical (pr,p) -> logical (row rr, chunk c),
    //      global byte offset (pre-swizzled source) ----
    size_t grA[2], grB[2];
#pragma unroll
    for (int i = 0; i < 2; ++i) {
        int pr = i * 64 + (tid >> 3);
        int p = tid & 7;
        int l = p ^ (pr & 7);
        int rr = 2 * pr + (l >> 2);
        int c = l & 3;
        grA[i] = (size_t)(m0 + rr) * (KPAD * 2) + (size_t)c * 16;
        grB[i] = (size_t)(n0 + rr) * (KPAD * 2) + (size_t)c * 16;
    }

    // ---- read-offset precompute (same involution) ----
    int aoff[8], boff[4];
#pragma unroll
    for (int mf = 0; mf < 8; ++mf) {
        int row = wm * 128 + mf * 16 + lm;
        int pr = row >> 1, l = (row & 1) * 4 + cfr, p = l ^ (pr & 7);
        aoff[mf] = pr * 128 + p * 16;
    }
#pragma unroll
    for (int nf = 0; nf < 4; ++nf) {
        int row = wn * 64 + nf * 16 + lm;
        int pr = row >> 1, l = (row & 1) * 4 + cfr, p = l ^ (pr & 7);
        boff[nf] = pr * 128 + p * 16;
    }

    auto stageA = [&](int js) {
        int seg = (js >= 44) ? 2 : (js >= 22 ? 1 : 0);
        const char* base = (const char*)((seg < 2) ? X0 : X1);
        size_t ko = (size_t)(js - seg * 22) * 64;
        char* l0 = smem + (js & 3) * 32768 + w * 1024;
        gload_lds16(base + grA[0] + ko, l0);
        gload_lds16(base + grA[1] + ko, l0 + 8192);
    };
    auto stageB = [&](int js) {
        int seg = (js >= 44) ? 2 : (js >= 22 ? 1 : 0);
        const char* base = (const char*)((seg == 1) ? W1 : W0);
        size_t ko = (size_t)(js - seg * 22) * 64;
        char* l0 = smem + (js & 3) * 32768 + 16384 + w * 1024;
        gload_lds16(base + grB[0] + ko, l0);
        gload_lds16(base + grB[1] + ko, l0 + 8192);
    };

    f32x4 acc[8][4];
#pragma unroll
    for (int mf = 0; mf < 8; ++mf)
#pragma unroll
        for (int nf = 0; nf < 4; ++nf) acc[mf][nf] = (f32x4){0.f, 0.f, 0.f, 0.f};

    // prologue: chunks 0 and 1 in flight (8 loads/wave), need chunk 0 -> vmcnt(4)
    stageA(0); stageB(0); stageA(1); stageB(1);
    asm volatile("s_waitcnt vmcnt(4)" ::: "memory");
    __builtin_amdgcn_s_barrier();
    __builtin_amdgcn_sched_barrier(0);

    for (int j = 0; j < NCHUNK; ++j) {
        const char* sa = smem + (j & 3) * 32768;
        const char* sb = sa + 16384;
        // ---- EVEN phase: A frags 0-3 + all B frags; MFMA quadrant mf0-3 ----
        f16x8 alo[4], bf[4];
#pragma unroll
        for (int mf = 0; mf < 4; ++mf)
            alo[mf] = *(const f16x8*)(sa + aoff[mf]);
#pragma unroll
        for (int nf = 0; nf < 4; ++nf)
            bf[nf] = *(const f16x8*)(sb + boff[nf]);
        if (j + 2 < NCHUNK) stageA(j + 2);
        __builtin_amdgcn_s_barrier();
        __builtin_amdgcn_sched_barrier(0);
        __builtin_amdgcn_s_setprio(1);
#pragma unroll
        for (int mf = 0; mf < 4; ++mf)
#pragma unroll
            for (int nf = 0; nf < 4; ++nf)
                acc[mf][nf] = __builtin_amdgcn_mfma_f32_16x16x32_f16(
                    alo[mf], bf[nf], acc[mf][nf], 0, 0, 0);
        __builtin_amdgcn_s_setprio(0);
        __builtin_amdgcn_s_barrier();
        __builtin_amdgcn_sched_barrier(0);
        // ---- ODD phase: A frags 4-7 (B reused); MFMA quadrant mf4-7 ----
        f16x8 ahi[4];
#pragma unroll
        for (int mf = 0; mf < 4; ++mf)
            ahi[mf] = *(const f16x8*)(sa + aoff[4 + mf]);
        if (j + 2 < NCHUNK) stageB(j + 2);
        if (j < NCHUNK - 2)
            asm volatile("s_waitcnt vmcnt(4)" ::: "memory");  // counted: next chunk ready
        else
            asm volatile("s_waitcnt vmcnt(0)" ::: "memory");  // tail drain
        __builtin_amdgcn_s_barrier();
        __builtin_amdgcn_sched_barrier(0);
        __builtin_amdgcn_s_setprio(1);
#pragma unroll
        for (int mf = 0; mf < 4; ++mf)
#pragma unroll
            for (int nf = 0; nf < 4; ++nf)
                acc[4 + mf][nf] = __builtin_amdgcn_mfma_f32_16x16x32_f16(
                    ahi[mf], bf[nf], acc[4 + mf][nf], 0, 0, 0);
        __builtin_amdgcn_s_setprio(0);
        __builtin_amdgcn_s_barrier();
        __builtin_amdgcn_sched_barrier(0);
    }

    // epilogue: C/D layout col=lane&15, row=(lane>>4)*4+reg
    const int crow0 = m0 + wm * 128 + (lane >> 4) * 4;
    const int ccol0 = n0 + wn * 64 + lm;
#pragma unroll
    for (int nf = 0; nf < 4; ++nf) {
        const float bias = b1[ccol0 + nf * 16];
#pragma unroll
        for (int mf = 0; mf < 8; ++mf) {
            f32x4 v = acc[mf][nf];
            const int r0 = crow0 + mf * 16;
#pragma unroll
            for (int r = 0; r < 4; ++r)
                C[(size_t)(r0 + r) * HK + ccol0 + nf * 16] = v[r] + bias;
        }
    }
}

// ---------------------------------------------------------------------------
// Kernel 3: sequential SNN scan over the T-chunk (unchanged, verified).
// ---------------------------------------------------------------------------
__global__ __launch_bounds__(256) void snn_scan(
    const float* __restrict__ Cur,         // (256, tc, 2048)
    const float* __restrict__ tau_m1,      // (512)
    const float* __restrict__ tau_n1,      // (512,4)
    float* __restrict__ st_d,              // (256,2048)
    float* __restrict__ st_m1,             // (256,512)
    unsigned long long* __restrict__ spk,  // (256,250,8)
    int t0, int tc) {
    const int b = blockIdx.x;
    const int tid = threadIdx.x;
    const int h0 = tid, h1 = tid + 256;
    const int wid = tid >> 6, lane = tid & 63;

    const float a0 = sigf(tau_m1[h0]);
    const float a1 = sigf(tau_m1[h1]);
    const float oma0 = 1.0f - a0, oma1 = 1.0f - a1;
    float4 tb0 = *(const float4*)(tau_n1 + h0 * 4);
    float4 tb1 = *(const float4*)(tau_n1 + h1 * 4);
    float be0[4] = {sigf(tb0.x), sigf(tb0.y), sigf(tb0.z), sigf(tb0.w)};
    float be1[4] = {sigf(tb1.x), sigf(tb1.y), sigf(tb1.z), sigf(tb1.w)};
    float ob0[4] = {1.0f - be0[0], 1.0f - be0[1], 1.0f - be0[2], 1.0f - be0[3]};
    float ob1[4] = {1.0f - be1[0], 1.0f - be1[1], 1.0f - be1[2], 1.0f - be1[3]};

    float d0[4], d1[4], m10, m11, s0, s1;
    if (t0 == 0) {
#pragma unroll
        for (int k = 0; k < 4; ++k) { d0[k] = 0.0f; d1[k] = 0.0f; }
        m10 = 0.0f; m11 = 0.0f; s0 = 0.0f; s1 = 0.0f;
    } else {
        float4 dv0 = *(const float4*)(st_d + (size_t)b * HK + tid * 4);
        float4 dv1 = *(const float4*)(st_d + (size_t)b * HK + 1024 + tid * 4);
        d0[0] = dv0.x; d0[1] = dv0.y; d0[2] = dv0.z; d0[3] = dv0.w;
        d1[0] = dv1.x; d1[1] = dv1.y; d1[2] = dv1.z; d1[3] = dv1.w;
        m10 = st_m1[(size_t)b * HID + h0];
        m11 = st_m1[(size_t)b * HID + h1];
        const unsigned long long* sp = spk + ((size_t)b * TSTEPS + (t0 - 1)) * 8;
        s0 = ((sp[wid] >> lane) & 1ull) ? 1.0f : 0.0f;
        s1 = ((sp[4 + wid] >> lane) & 1ull) ? 1.0f : 0.0f;
    }

    const float* cbase = Cur + (size_t)b * tc * HK;
    float4 c0 = *(const float4*)(cbase + tid * 4);
    float4 c1 = *(const float4*)(cbase + 1024 + tid * 4);

    for (int tt = 0; tt < tc; ++tt) {
        float4 n0v, n1v;
        if (tt + 1 < tc) {
            const float* p = cbase + (size_t)(tt + 1) * HK;
            n0v = *(const float4*)(p + tid * 4);
            n1v = *(const float4*)(p + 1024 + tid * 4);
        } else { n0v = c0; n1v = c1; }

        d0[0] = be0[0] * d0[0] + ob0[0] * c0.x;
        d0[1] = be0[1] * d0[1] + ob0[1] * c0.y;
        d0[2] = be0[2] * d0[2] + ob0[2] * c0.z;
        d0[3] = be0[3] * d0[3] + ob0[3] * c0.w;
        d1[0] = be1[0] * d1[0] + ob1[0] * c1.x;
        d1[1] = be1[1] * d1[1] + ob1[1] * c1.y;
        d1[2] = be1[2] * d1[2] + ob1[2] * c1.z;
        d1[3] = be1[3] * d1[3] + ob1[3] * c1.w;
        float l0 = (d0[0] + d0[1]) + (d0[2] + d0[3]);
        float l1 = (d1[0] + d1[1]) + (d1[2] + d1[3]);

        m10 = a0 * m10 + oma0 * l0 - s0;
        m11 = a1 * m11 + oma1 * l1 - s1;
        bool sp0 = m10 > 1.0f;
        bool sp1 = m11 > 1.0f;
        s0 = sp0 ? 1.0f : 0.0f;
        s1 = sp1 ? 1.0f : 0.0f;

        unsigned long long mk0 = __ballot(sp0);
        unsigned long long mk1 = __ballot(sp1);
        if (lane == 0) {
            unsigned long long* ox = spk + ((size_t)b * TSTEPS + (t0 + tt)) * 8;
            ox[wid] = mk0;
            ox[4 + wid] = mk1;
        }
        c0 = n0v; c1 = n1v;
    }

    float4 dv0 = {d0[0], d0[1], d0[2], d0[3]};
    float4 dv1 = {d1[0], d1[1], d1[2], d1[3]};
    *(float4*)(st_d + (size_t)b * HK + tid * 4) = dv0;
    *(float4*)(st_d + (size_t)b * HK + 1024 + tid * 4) = dv1;
    st_m1[(size_t)b * HID + h0] = m10;
    st_m1[(size_t)b * HID + h1] = m11;
}

// ---------------------------------------------------------------------------
// Kernel 4: out(b,t,o) = b2(o) + sum_h spk(b,t,h)*w2(o,h), bit-sparse.
// ---------------------------------------------------------------------------
__global__ __launch_bounds__(256) void spk_gemm(
    const unsigned long long* __restrict__ spk,  // (256,250,8)
    const float* __restrict__ w2,                // (20,512)
    const float* __restrict__ b2,                // (20)
    float* __restrict__ Y) {                     // (256,250,20)
    __shared__ float w2t[512][21];
    const int t = blockIdx.x;
    const int b = threadIdx.x;
    for (int i = threadIdx.x; i < HID * NOUT; i += 256) {
        int o = i / HID;
        int h = i - o * HID;
        w2t[h][o] = w2[i];
    }
    __syncthreads();
    float acc[NOUT];
#pragma unroll
    for (int o = 0; o < NOUT; ++o) acc[o] = b2[o];
    const unsigned long long* sp = spk + ((size_t)b * TSTEPS + t) * 8;
#pragma unroll
    for (int w = 0; w < 8; ++w) {
        unsigned long long m = sp[w];
        while (m) {
            int i = __ffsll((long long)m) - 1;
            m &= m - 1;
            const float* col = &w2t[w * 64 + i][0];
#pragma unroll
            for (int o = 0; o < NOUT; ++o) acc[o] += col[o];
        }
    }
    float* outp = Y + ((size_t)b * TSTEPS + t) * NOUT;
#pragma unroll
    for (int o = 0; o < NOUT; ++o) outp[o] = acc[o];
}

// ---------------------------------------------------------------------------
// Kernel 5: in-place leaky readout filter per (b,o) over t.
// ---------------------------------------------------------------------------
__global__ __launch_bounds__(256) void filter_out(
    float* __restrict__ Y, const float* __restrict__ tau_m2) {
    int gid = blockIdx.x * 256 + threadIdx.x;
    if (gid >= BATCH * NOUT) return;
    int b = gid / NOUT;
    int o = gid - b * NOUT;
    float a2 = sigf(tau_m2[o]);
    float oma = 1.0f - a2;
    float m2 = 0.0f;
    float* p = Y + (size_t)b * TSTEPS * NOUT + o;
    for (int t = 0; t < TSTEPS; ++t) {
        m2 = a2 * m2 + oma * p[(size_t)t * NOUT];
        p[(size_t)t * NOUT] = m2;
    }
}

// ---------------------------------------------------------------------------
extern "C" void kernel_launch(void* const* d_in, const int* in_sizes, int n_in,
                              void* d_out, int out_size, void* d_ws, size_t ws_size,
                              hipStream_t stream) {
    const float* x      = (const float*)d_in[0];
    const float* w1     = (const float*)d_in[1];
    const float* b1     = (const float*)d_in[2];
    const float* tau_m1 = (const float*)d_in[3];
    const float* tau_n1 = (const float*)d_in[4];
    const float* mask   = (const float*)d_in[5];
    const float* w2     = (const float*)d_in[6];
    const float* b2     = (const float*)d_in[7];
    const float* tau_m2 = (const float*)d_in[8];
    float* out = (float*)d_out;

    char* ws = (char*)d_ws;
    size_t off = 0;
    auto walloc = [&](size_t bytes) -> void* {
        void* p = ws + off;
        off += (bytes + 255) & ~(size_t)255;
        return p;
    };
    _Float16* W0 = (_Float16*)walloc((size_t)HK * KPAD * 2);          // 2.88 MB
    _Float16* W1 = (_Float16*)walloc((size_t)HK * KPAD * 2);          // 2.88 MB
    unsigned long long* spk =
        (unsigned long long*)walloc((size_t)BATCH * TSTEPS * 8 * 8);  // 4.10 MB
    float* st_d  = (float*)walloc((size_t)BATCH * HK * 4);            // 2.10 MB
    float* st_m1 = (float*)walloc((size_t)BATCH * HID * 4);           // 0.52 MB

    // per-timestep: cur (fp32) + X0 + X1 (fp16)
    const size_t perT = (size_t)BATCH * HK * 4 + 2 * (size_t)BATCH * KPAD * 2;
    size_t avail = (ws_size > off + 4096) ? ws_size - off - 4096 : 0;
    int Tc = (int)(avail / perT);
    if (Tc > TSTEPS) Tc = TSTEPS;
    if (Tc < 1) Tc = 1;
    _Float16* X0 = (_Float16*)walloc((size_t)BATCH * Tc * KPAD * 2);
    _Float16* X1 = (_Float16*)walloc((size_t)BATCH * Tc * KPAD * 2);
    float* cur   = (float*)walloc((size_t)BATCH * Tc * HK * 4);

    split_w<<<HK, 192, 0, stream>>>(w1, mask, W0, W1);

    for (int t0 = 0; t0 < TSTEPS; t0 += Tc) {
        int tc = (TSTEPS - t0 < Tc) ? (TSTEPS - t0) : Tc;
        split_x<<<BATCH * tc, 192, 0, stream>>>(x, X0, X1, t0, tc);
        // 256x256 tiles: M = 256*tc (divisible by 256 for any tc), N = 2048
        dim3 grid(8 * tc);
        gemm_f16<<<grid, 512, 131072, stream>>>(X0, X1, W0, W1, b1, cur);
        snn_scan<<<BATCH, 256, 0, stream>>>(cur, tau_m1, tau_n1, st_d, st_m1,
                                            spk, t0, tc);
    }
    spk_gemm<<<TSTEPS, 256, 0, stream>>>(spk, w2, b2, out);
    filter_out<<<(BATCH * NOUT + 255) / 256, 256, 0, stream>>>(out, tau_m2);
}